// Round 2
// baseline (104.801 us; speedup 1.0000x reference)
//
#include <hip/hip_runtime.h>

#define B_ 4
#define L_ 2048
#define MD_ 512
#define KV_ 64
#define NKT_ (L_ / 64)

typedef unsigned short u16;
typedef unsigned char u8;
typedef unsigned int u32;
typedef __attribute__((ext_vector_type(8))) short bf16x8;
typedef __attribute__((ext_vector_type(4))) float f32x4;
typedef __attribute__((ext_vector_type(4))) u32 u32x4;
typedef __attribute__((ext_vector_type(4))) u16 u16x4;

#define INV_T 0.044194173824159216f  /* 1/sqrt(512) */

static __device__ __forceinline__ u16 f2bf(float x) {
  u32 u = __float_as_uint(x);
  return (u16)((u + 0x7FFFu + ((u >> 16) & 1u)) >> 16);
}
static __device__ __forceinline__ f32x4 zero4() {
  f32x4 z = {0.f, 0.f, 0.f, 0.f};
  return z;
}
static __device__ __forceinline__ f32x4 mfma16(bf16x8 a, bf16x8 b, f32x4 c) {
  return __builtin_amdgcn_mfma_f32_16x16x32_bf16(a, b, c, 0, 0, 0);
}

// ---------------------------------------------------------------------------
// Weight prep: WtT[p][c][d] = bf16(W_p[c][d]) (B-operand layout, 520-stride pad)
//              WpT[m][d]   = bf16(sum_h Wp[m][h*64+d]) (head-fold, 72-stride)
//              bqkv[192]   = concat(bq,bk,bv)
// ---------------------------------------------------------------------------
__global__ __launch_bounds__(256) void mha_prep(
    const float* __restrict__ Wq, const float* __restrict__ Wk,
    const float* __restrict__ Wv, const float* __restrict__ bq,
    const float* __restrict__ bk, const float* __restrict__ bv,
    const float* __restrict__ Wp, u16* __restrict__ WtT,
    float* __restrict__ bqkv, u16* __restrict__ WpT) {
  int t = blockIdx.x * 256 + threadIdx.x;
  if (t < 3 * 64 * 512) {
    int p = t >> 15, c = (t >> 9) & 63, d = t & 511;
    const float* W = (p == 0) ? Wq : ((p == 1) ? Wk : Wv);
    WtT[(p * 64 + c) * 520 + d] = f2bf(W[c * 512 + d]);
  } else if (t < 3 * 64 * 512 + 512 * 64) {
    int i = t - 3 * 64 * 512;
    int m = i >> 6, d = i & 63;
    float s = 0.f;
#pragma unroll
    for (int h = 0; h < 8; h++) s += Wp[m * 512 + h * 64 + d];
    WpT[m * 72 + d] = f2bf(s);
  } else if (t < 3 * 64 * 512 + 512 * 64 + 192) {
    int j = t - (3 * 64 * 512 + 512 * 64);
    int p = j >> 6;
    const float* bb = (p == 0) ? bq : ((p == 1) ? bk : bv);
    bqkv[j] = bb[j & 63];
  }
}

// ---------------------------------------------------------------------------
// Fused projections: rows r0..r0+31 of q,k,v (fp32) -> qp/kp/vp bf16 (B*L x 64)
// ---------------------------------------------------------------------------
__global__ __launch_bounds__(256) void mha_proj(
    const float* __restrict__ q, const float* __restrict__ k,
    const float* __restrict__ v, const u16* __restrict__ WtT,
    const float* __restrict__ bqkv, u16* __restrict__ qkv16) {
  __shared__ __align__(16) u16 X[3][32][520];
  const int tid = threadIdx.x;
  const int r0 = blockIdx.x * 32;
#pragma unroll 4
  for (int i = 0; i < 48; i++) {
    int e = tid + i * 256;  // 12288 float4 tasks
    int p = e >> 12, r = (e >> 7) & 31, dq = (e & 127) << 2;
    const float* src = (p == 0) ? q : ((p == 1) ? k : v);
    f32x4 xv = *(const f32x4*)(src + (size_t)(r0 + r) * 512 + dq);
    u16x4 w4 = {f2bf(xv[0]), f2bf(xv[1]), f2bf(xv[2]), f2bf(xv[3])};
    *(u16x4*)&X[p][r][dq] = w4;
  }
  __syncthreads();
  const int w = tid >> 6, l = tid & 63, g = l >> 4, li = l & 15;
  const int mt = w & 1, half = w >> 1;
  f32x4 acc[6];
#pragma unroll
  for (int i = 0; i < 6; i++) acc[i] = zero4();

  if (half == 0) {
#pragma unroll 4
    for (int ks = 0; ks < 16; ks++) {
      const int ko = g * 8 + ks * 32;
      bf16x8 a0 = *(const bf16x8*)&X[0][mt * 16 + li][ko];
      bf16x8 a1 = *(const bf16x8*)&X[1][mt * 16 + li][ko];
      acc[0] = mfma16(a0, *(const bf16x8*)(WtT + (0 * 64 + 0 + li) * 520 + ko), acc[0]);
      acc[1] = mfma16(a0, *(const bf16x8*)(WtT + (0 * 64 + 16 + li) * 520 + ko), acc[1]);
      acc[2] = mfma16(a0, *(const bf16x8*)(WtT + (0 * 64 + 32 + li) * 520 + ko), acc[2]);
      acc[3] = mfma16(a0, *(const bf16x8*)(WtT + (0 * 64 + 48 + li) * 520 + ko), acc[3]);
      acc[4] = mfma16(a1, *(const bf16x8*)(WtT + (1 * 64 + 0 + li) * 520 + ko), acc[4]);
      acc[5] = mfma16(a1, *(const bf16x8*)(WtT + (1 * 64 + 16 + li) * 520 + ko), acc[5]);
    }
  } else {
#pragma unroll 4
    for (int ks = 0; ks < 16; ks++) {
      const int ko = g * 8 + ks * 32;
      bf16x8 a1 = *(const bf16x8*)&X[1][mt * 16 + li][ko];
      bf16x8 a2 = *(const bf16x8*)&X[2][mt * 16 + li][ko];
      acc[0] = mfma16(a1, *(const bf16x8*)(WtT + (1 * 64 + 32 + li) * 520 + ko), acc[0]);
      acc[1] = mfma16(a1, *(const bf16x8*)(WtT + (1 * 64 + 48 + li) * 520 + ko), acc[1]);
      acc[2] = mfma16(a2, *(const bf16x8*)(WtT + (2 * 64 + 0 + li) * 520 + ko), acc[2]);
      acc[3] = mfma16(a2, *(const bf16x8*)(WtT + (2 * 64 + 16 + li) * 520 + ko), acc[3]);
      acc[4] = mfma16(a2, *(const bf16x8*)(WtT + (2 * 64 + 32 + li) * 520 + ko), acc[4]);
      acc[5] = mfma16(a2, *(const bf16x8*)(WtT + (2 * 64 + 48 + li) * 520 + ko), acc[5]);
    }
  }
#pragma unroll
  for (int i = 0; i < 6; i++) {
    int nt = half * 6 + i;
    int p = nt >> 2, c4 = nt & 3;
    float bias = bqkv[nt * 16 + li];
    u16* outp = qkv16 + (size_t)p * (B_ * L_ * KV_);
#pragma unroll
    for (int j = 0; j < 4; j++) {
      int row = r0 + mt * 16 + g * 4 + j;
      outp[(size_t)row * 64 + c4 * 16 + li] = f2bf(acc[i][j] + bias);
    }
  }
}

// ---------------------------------------------------------------------------
// Flash attention: grid (64 q-tiles, 4 batches), block 128 = 2 waves x 16 rows.
// K/V/mask tiles register-prefetched one iteration ahead, staged to LDS.
// Mask is int32 (harness passes jnp.bool_ as int32): 16 ints/thread/tile,
// packed to bytes in registers before the LDS store.
// V stored transposed [d][k] so PV B-fragments are single b128 reads.
// ---------------------------------------------------------------------------
#define PREF_TILE(KT)                                                          \
  do {                                                                         \
    size_t kb_ = brow + (size_t)(KT) * 64;                                     \
    _Pragma("unroll") for (int i_ = 0; i_ < 4; i_++) {                         \
      int e_ = tid + i_ * 128;                                                 \
      kpre[i_] = *(const u32x4*)(kp + (kb_ + (e_ >> 3)) * 64 + (e_ & 7) * 8);  \
    }                                                                          \
    _Pragma("unroll") for (int i_ = 0; i_ < 2; i_++) {                         \
      int task_ = tid * 2 + i_;                                                \
      int kpp_ = task_ >> 3, dc_ = task_ & 7;                                  \
      vpre0[i_] = *(const u32x4*)(vp + (kb_ + 2 * kpp_) * 64 + dc_ * 8);       \
      vpre1[i_] = *(const u32x4*)(vp + (kb_ + 2 * kpp_ + 1) * 64 + dc_ * 8);   \
    }                                                                          \
    const u32* mrow_ = (const u32*)mask +                                      \
                       (brow + q0 + (tid >> 2)) * (size_t)L_ +                 \
                       (size_t)(KT) * 64 + (tid & 3) * 16;                     \
    _Pragma("unroll") for (int i_ = 0; i_ < 4; i_++) {                         \
      mpre[i_] = *(const u32x4*)(mrow_ + i_ * 4);                              \
    }                                                                          \
  } while (0)

__global__ __launch_bounds__(128) void mha_attn(const u16* __restrict__ qkv16,
                                                const int* __restrict__ mask,
                                                u16* __restrict__ aout) {
  __shared__ __align__(16) u16 Klds[64][72];
  __shared__ __align__(16) u16 Vlds[64][72];  // transposed: [d][k]
  __shared__ __align__(16) u16 Plds[2][16][72];
  __shared__ __align__(16) u32x4 Mlds[128];
  const int tid = threadIdx.x;
  const int w = tid >> 6, l = tid & 63, g = l >> 4, li = l & 15;
  const int b = blockIdx.y;
  const int q0 = blockIdx.x * 32;
  const u16* qp = qkv16;
  const u16* kp = qkv16 + (size_t)(B_ * L_ * KV_);
  const u16* vp = qkv16 + (size_t)2 * (B_ * L_ * KV_);
  const size_t brow = (size_t)b * L_;

  bf16x8 qf0 = *(const bf16x8*)(qp + (brow + q0 + w * 16 + li) * 64 + g * 8);
  bf16x8 qf1 = *(const bf16x8*)(qp + (brow + q0 + w * 16 + li) * 64 + g * 8 + 32);

  f32x4 o[4];
  float m_[4], lsum[4];
#pragma unroll
  for (int i = 0; i < 4; i++) {
    o[i] = zero4();
    m_[i] = -1e30f;
    lsum[i] = 0.f;
  }
  u32x4 kpre[4], vpre0[2], vpre1[2], mpre[4];
  PREF_TILE(0);

  for (int kt = 0; kt < NKT_; kt++) {
    __syncthreads();  // previous iteration's LDS reads done
    // ---- write staged tile to LDS ----
#pragma unroll
    for (int i = 0; i < 4; i++) {
      int e = tid + i * 128;
      *(u32x4*)&Klds[e >> 3][(e & 7) * 8] = kpre[i];
    }
#pragma unroll
    for (int i = 0; i < 2; i++) {
      int task = tid * 2 + i;
      int kpp = task >> 3, dc = task & 7;
#pragma unroll
      for (int j = 0; j < 8; j++) {
        u32 lo = (vpre0[i][j >> 1] >> ((j & 1) * 16)) & 0xFFFFu;
        u32 hi = (vpre1[i][j >> 1] >> ((j & 1) * 16)) & 0xFFFFu;
        *(u32*)&Vlds[dc * 8 + j][kpp * 2] = lo | (hi << 16);
      }
    }
    {  // pack 16 int32 mask values -> 16 bytes
      u32x4 pk;
#pragma unroll
      for (int c = 0; c < 4; c++) {
        u32 bb = 0;
#pragma unroll
        for (int j = 0; j < 4; j++) bb |= (mpre[c][j] ? 1u : 0u) << (8 * j);
        pk[c] = bb;
      }
      Mlds[tid] = pk;
    }
    if (kt + 1 < NKT_) { PREF_TILE(kt + 1); }  // hide HBM latency under compute
    __syncthreads();

    // ---- S = Q K^T (strip 16 q-rows x 64 keys per wave) ----
    f32x4 s[4];
#pragma unroll
    for (int nt = 0; nt < 4; nt++) {
      s[nt] = zero4();
      bf16x8 b0 = *(const bf16x8*)&Klds[nt * 16 + li][g * 8];
      bf16x8 b1 = *(const bf16x8*)&Klds[nt * 16 + li][g * 8 + 32];
      s[nt] = mfma16(qf0, b0, s[nt]);
      s[nt] = mfma16(qf1, b1, s[nt]);
    }
    // ---- mask + online softmax ----
    const u8* mb = (const u8*)Mlds;
    float p_[4][4];
#pragma unroll
    for (int j = 0; j < 4; j++) {
      int mrow = (w * 16 + g * 4 + j) * 64;
      float mx = -1e30f;
#pragma unroll
      for (int nt = 0; nt < 4; nt++) {
        float sv = s[nt][j] * INV_T;
        if (mb[mrow + nt * 16 + li]) sv = -1e30f;
        p_[nt][j] = sv;
        mx = fmaxf(mx, sv);
      }
#pragma unroll
      for (int d = 1; d < 16; d <<= 1) mx = fmaxf(mx, __shfl_xor(mx, d, 64));
      float mn = fmaxf(m_[j], mx);
      float esc = __expf(m_[j] - mn);
      m_[j] = mn;
      float rs = 0.f;
#pragma unroll
      for (int nt = 0; nt < 4; nt++) {
        float pv = __expf(p_[nt][j] - mn);
        p_[nt][j] = pv;
        rs += pv;
      }
#pragma unroll
      for (int d = 1; d < 16; d <<= 1) rs += __shfl_xor(rs, d, 64);
      lsum[j] = lsum[j] * esc + rs;
#pragma unroll
      for (int dt = 0; dt < 4; dt++) o[dt][j] *= esc;
    }
    // ---- P -> LDS (D-layout scatter), then PV via MFMA ----
#pragma unroll
    for (int nt = 0; nt < 4; nt++)
#pragma unroll
      for (int j = 0; j < 4; j++)
        Plds[w][g * 4 + j][nt * 16 + li] = f2bf(p_[nt][j]);
#pragma unroll
    for (int ks = 0; ks < 2; ks++) {
      bf16x8 pa = *(const bf16x8*)&Plds[w][li][g * 8 + ks * 32];
#pragma unroll
      for (int dt = 0; dt < 4; dt++) {
        bf16x8 vb = *(const bf16x8*)&Vlds[dt * 16 + li][g * 8 + ks * 32];
        o[dt] = mfma16(pa, vb, o[dt]);
      }
    }
  }
  // ---- normalize + store bf16 ----
#pragma unroll
  for (int j = 0; j < 4; j++) {
    float inv = 1.f / lsum[j];
    size_t row = brow + q0 + w * 16 + g * 4 + j;
#pragma unroll
    for (int dt = 0; dt < 4; dt++)
      aout[row * 64 + dt * 16 + li] = f2bf(o[dt][j] * inv);
  }
}

// ---------------------------------------------------------------------------
// Final: out[r][m] = sum_d aout[r][d] * WpEff[m][d] + bp[m]   (fp32 out)
// ---------------------------------------------------------------------------
__global__ __launch_bounds__(128) void mha_fin(const u16* __restrict__ aout,
                                               const u16* __restrict__ WpT,
                                               const float* __restrict__ bp,
                                               float* __restrict__ out) {
  const int tid = threadIdx.x;
  const int w = tid >> 6, l = tid & 63, g = l >> 4, li = l & 15;
  const size_t r0 = (size_t)blockIdx.x * 32;
  const u16* ar = aout + (r0 + w * 16 + li) * 64;
  bf16x8 a0 = *(const bf16x8*)(ar + g * 8);
  bf16x8 a1 = *(const bf16x8*)(ar + g * 8 + 32);
#pragma unroll 4
  for (int nt = 0; nt < 32; nt++) {
    bf16x8 b0 = *(const bf16x8*)(WpT + (nt * 16 + li) * 72 + g * 8);
    bf16x8 b1 = *(const bf16x8*)(WpT + (nt * 16 + li) * 72 + g * 8 + 32);
    f32x4 acc = zero4();
    acc = mfma16(a0, b0, acc);
    acc = mfma16(a1, b1, acc);
    float bias = bp[nt * 16 + li];
#pragma unroll
    for (int j = 0; j < 4; j++)
      out[(r0 + w * 16 + g * 4 + j) * 512 + nt * 16 + li] = acc[j] + bias;
  }
}

extern "C" void kernel_launch(void* const* d_in, const int* in_sizes, int n_in,
                              void* d_out, int out_size, void* d_ws,
                              size_t ws_size, hipStream_t stream) {
  const float* q = (const float*)d_in[0];
  const float* k = (const float*)d_in[1];
  const float* v = (const float*)d_in[2];
  const int* mask = (const int*)d_in[3];  // jnp.bool_ -> int32 per harness
  const float* Wq = (const float*)d_in[4];
  const float* bq = (const float*)d_in[5];
  const float* Wk = (const float*)d_in[6];
  const float* bk = (const float*)d_in[7];
  const float* Wv = (const float*)d_in[8];
  const float* bv = (const float*)d_in[9];
  const float* Wp = (const float*)d_in[10];
  const float* bp = (const float*)d_in[11];

  char* ws = (char*)d_ws;
  u16* qkv16 = (u16*)(ws + 0);            // 3 * 1 MiB bf16 qp/kp/vp
  u16* aout = (u16*)(ws + 3145728);       // 1 MiB bf16 attention out
  u16* WtT = (u16*)(ws + 4194304);        // [3][64][520] bf16
  float* bqkv = (float*)(ws + 4393984);   // [192] f32
  u16* WpT = (u16*)(ws + 4394752);        // [512][72] bf16

  mha_prep<<<dim3(513), dim3(256), 0, stream>>>(Wq, Wk, Wv, bq, bk, bv, Wp,
                                                WtT, bqkv, WpT);
  mha_proj<<<dim3(256), dim3(256), 0, stream>>>(q, k, v, WtT, bqkv, qkv16);
  mha_attn<<<dim3(64, 4), dim3(128), 0, stream>>>(qkv16, mask, aout);
  mha_fin<<<dim3(256), dim3(128), 0, stream>>>(aout, WpT, bp, (float*)d_out);
}

// Round 3
// 71.155 us; speedup vs baseline: 1.4728x; 1.4728x over previous
//
#include <hip/hip_runtime.h>

#define B_ 4
#define L_ 2048
#define MD_ 512
#define KV_ 64
#define NKT_ (L_ / 64)
#define KSPLIT 8
#define KT_PER (NKT_ / KSPLIT)  /* 4 key-tiles of 64 per split */

typedef unsigned short u16;
typedef unsigned char u8;
typedef unsigned int u32;
typedef unsigned long long u64;
typedef __attribute__((ext_vector_type(8))) short bf16x8;
typedef __attribute__((ext_vector_type(4))) float f32x4;
typedef __attribute__((ext_vector_type(4))) u32 u32x4;
typedef __attribute__((ext_vector_type(4))) u16 u16x4;

#define INV_T 0.044194173824159216f  /* 1/sqrt(512) */

static __device__ __forceinline__ u16 f2bf(float x) {
  u32 u = __float_as_uint(x);
  return (u16)((u + 0x7FFFu + ((u >> 16) & 1u)) >> 16);
}
static __device__ __forceinline__ f32x4 zero4() {
  f32x4 z = {0.f, 0.f, 0.f, 0.f};
  return z;
}
static __device__ __forceinline__ f32x4 mfma16(bf16x8 a, bf16x8 b, f32x4 c) {
  return __builtin_amdgcn_mfma_f32_16x16x32_bf16(a, b, c, 0, 0, 0);
}

// ---------------------------------------------------------------------------
// Weight prep: WtT[p][c][d] = bf16(W_p[c][d]) (B-operand layout, 520-stride pad)
//              WpT[m][d]   = bf16(sum_h Wp[m][h*64+d]) (head-fold, 72-stride)
//              bqkv[192]   = concat(bq,bk,bv)
// ---------------------------------------------------------------------------
__global__ __launch_bounds__(256) void mha_prep(
    const float* __restrict__ Wq, const float* __restrict__ Wk,
    const float* __restrict__ Wv, const float* __restrict__ bq,
    const float* __restrict__ bk, const float* __restrict__ bv,
    const float* __restrict__ Wp, u16* __restrict__ WtT,
    float* __restrict__ bqkv, u16* __restrict__ WpT) {
  int t = blockIdx.x * 256 + threadIdx.x;
  if (t < 3 * 64 * 512) {
    int p = t >> 15, c = (t >> 9) & 63, d = t & 511;
    const float* W = (p == 0) ? Wq : ((p == 1) ? Wk : Wv);
    WtT[(p * 64 + c) * 520 + d] = f2bf(W[c * 512 + d]);
  } else if (t < 3 * 64 * 512 + 512 * 64) {
    int i = t - 3 * 64 * 512;
    int m = i >> 6, d = i & 63;
    float s = 0.f;
#pragma unroll
    for (int h = 0; h < 8; h++) s += Wp[m * 512 + h * 64 + d];
    WpT[m * 72 + d] = f2bf(s);
  } else if (t < 3 * 64 * 512 + 512 * 64 + 192) {
    int j = t - (3 * 64 * 512 + 512 * 64);
    int p = j >> 6;
    const float* bb = (p == 0) ? bq : ((p == 1) ? bk : bv);
    bqkv[j] = bb[j & 63];
  }
}

// ---------------------------------------------------------------------------
// Fused projections: rows r0..r0+31 of q,k,v (fp32) -> qp/kp/vp bf16 (B*L x 64)
// ---------------------------------------------------------------------------
__global__ __launch_bounds__(256) void mha_proj(
    const float* __restrict__ q, const float* __restrict__ k,
    const float* __restrict__ v, const u16* __restrict__ WtT,
    const float* __restrict__ bqkv, u16* __restrict__ qkv16) {
  __shared__ __align__(16) u16 X[3][32][520];
  const int tid = threadIdx.x;
  const int r0 = blockIdx.x * 32;
#pragma unroll 4
  for (int i = 0; i < 48; i++) {
    int e = tid + i * 256;  // 12288 float4 tasks
    int p = e >> 12, r = (e >> 7) & 31, dq = (e & 127) << 2;
    const float* src = (p == 0) ? q : ((p == 1) ? k : v);
    f32x4 xv = *(const f32x4*)(src + (size_t)(r0 + r) * 512 + dq);
    u16x4 w4 = {f2bf(xv[0]), f2bf(xv[1]), f2bf(xv[2]), f2bf(xv[3])};
    *(u16x4*)&X[p][r][dq] = w4;
  }
  __syncthreads();
  const int w = tid >> 6, l = tid & 63, g = l >> 4, li = l & 15;
  const int mt = w & 1, half = w >> 1;
  f32x4 acc[6];
#pragma unroll
  for (int i = 0; i < 6; i++) acc[i] = zero4();

  if (half == 0) {
#pragma unroll 4
    for (int ks = 0; ks < 16; ks++) {
      const int ko = g * 8 + ks * 32;
      bf16x8 a0 = *(const bf16x8*)&X[0][mt * 16 + li][ko];
      bf16x8 a1 = *(const bf16x8*)&X[1][mt * 16 + li][ko];
      acc[0] = mfma16(a0, *(const bf16x8*)(WtT + (0 * 64 + 0 + li) * 520 + ko), acc[0]);
      acc[1] = mfma16(a0, *(const bf16x8*)(WtT + (0 * 64 + 16 + li) * 520 + ko), acc[1]);
      acc[2] = mfma16(a0, *(const bf16x8*)(WtT + (0 * 64 + 32 + li) * 520 + ko), acc[2]);
      acc[3] = mfma16(a0, *(const bf16x8*)(WtT + (0 * 64 + 48 + li) * 520 + ko), acc[3]);
      acc[4] = mfma16(a1, *(const bf16x8*)(WtT + (1 * 64 + 0 + li) * 520 + ko), acc[4]);
      acc[5] = mfma16(a1, *(const bf16x8*)(WtT + (1 * 64 + 16 + li) * 520 + ko), acc[5]);
    }
  } else {
#pragma unroll 4
    for (int ks = 0; ks < 16; ks++) {
      const int ko = g * 8 + ks * 32;
      bf16x8 a1 = *(const bf16x8*)&X[1][mt * 16 + li][ko];
      bf16x8 a2 = *(const bf16x8*)&X[2][mt * 16 + li][ko];
      acc[0] = mfma16(a1, *(const bf16x8*)(WtT + (1 * 64 + 32 + li) * 520 + ko), acc[0]);
      acc[1] = mfma16(a1, *(const bf16x8*)(WtT + (1 * 64 + 48 + li) * 520 + ko), acc[1]);
      acc[2] = mfma16(a2, *(const bf16x8*)(WtT + (2 * 64 + 0 + li) * 520 + ko), acc[2]);
      acc[3] = mfma16(a2, *(const bf16x8*)(WtT + (2 * 64 + 16 + li) * 520 + ko), acc[3]);
      acc[4] = mfma16(a2, *(const bf16x8*)(WtT + (2 * 64 + 32 + li) * 520 + ko), acc[4]);
      acc[5] = mfma16(a2, *(const bf16x8*)(WtT + (2 * 64 + 48 + li) * 520 + ko), acc[5]);
    }
  }
#pragma unroll
  for (int i = 0; i < 6; i++) {
    int nt = half * 6 + i;
    int p = nt >> 2, c4 = nt & 3;
    float bias = bqkv[nt * 16 + li];
    u16* outp = qkv16 + (size_t)p * (B_ * L_ * KV_);
#pragma unroll
    for (int j = 0; j < 4; j++) {
      int row = r0 + mt * 16 + g * 4 + j;
      outp[(size_t)row * 64 + c4 * 16 + li] = f2bf(acc[i][j] + bias);
    }
  }
}

// ---------------------------------------------------------------------------
// Flash attention, k-split by 8: grid (64 q-tiles, 4 batches, 8 splits),
// block 128 = 2 waves x 16 q-rows, 4 key-tiles of 64 per block.
// Emits UNNORMALIZED partials (o fp32, m, l) for the combine kernel.
// Mask int32 prefetched 16/thread, packed to a 1-bit-per-key LDS bitfield.
// ---------------------------------------------------------------------------
#define PREF_TILE(KT)                                                          \
  do {                                                                         \
    size_t kb_ = brow + (size_t)(KT) * 64;                                     \
    _Pragma("unroll") for (int i_ = 0; i_ < 4; i_++) {                         \
      int e_ = tid + i_ * 128;                                                 \
      kpre[i_] = *(const u32x4*)(kp + (kb_ + (e_ >> 3)) * 64 + (e_ & 7) * 8);  \
    }                                                                          \
    _Pragma("unroll") for (int i_ = 0; i_ < 2; i_++) {                         \
      int task_ = tid * 2 + i_;                                                \
      int kpp_ = task_ >> 3, dc_ = task_ & 7;                                  \
      vpre0[i_] = *(const u32x4*)(vp + (kb_ + 2 * kpp_) * 64 + dc_ * 8);       \
      vpre1[i_] = *(const u32x4*)(vp + (kb_ + 2 * kpp_ + 1) * 64 + dc_ * 8);   \
    }                                                                          \
    const u32* mrow_ = (const u32*)mask +                                      \
                       (brow + q0 + (tid >> 2)) * (size_t)L_ +                 \
                       (size_t)(KT) * 64 + (tid & 3) * 16;                     \
    _Pragma("unroll") for (int i_ = 0; i_ < 4; i_++) {                         \
      mpre[i_] = *(const u32x4*)(mrow_ + i_ * 4);                              \
    }                                                                          \
  } while (0)

__global__ __launch_bounds__(128) void mha_attn(
    const u16* __restrict__ qkv16, const int* __restrict__ mask,
    float* __restrict__ po, float* __restrict__ pm, float* __restrict__ pl) {
  __shared__ __align__(16) u16 Klds[64][72];
  __shared__ __align__(16) u16 Vlds[64][72];  // transposed: [d][k]
  __shared__ __align__(16) u16 Plds[2][16][72];
  __shared__ __align__(8) u16 Mbits[32][4];  // 1 bit per key, u64 per q-row
  const int tid = threadIdx.x;
  const int w = tid >> 6, l = tid & 63, g = l >> 4, li = l & 15;
  const int b = blockIdx.y;
  const int q0 = blockIdx.x * 32;
  const int s = blockIdx.z;
  const u16* qp = qkv16;
  const u16* kp = qkv16 + (size_t)(B_ * L_ * KV_);
  const u16* vp = qkv16 + (size_t)2 * (B_ * L_ * KV_);
  const size_t brow = (size_t)b * L_;

  bf16x8 qf0 = *(const bf16x8*)(qp + (brow + q0 + w * 16 + li) * 64 + g * 8);
  bf16x8 qf1 = *(const bf16x8*)(qp + (brow + q0 + w * 16 + li) * 64 + g * 8 + 32);

  f32x4 o[4];
  float m_[4], lsum[4];
#pragma unroll
  for (int i = 0; i < 4; i++) {
    o[i] = zero4();
    m_[i] = -1e30f;
    lsum[i] = 0.f;
  }
  u32x4 kpre[4], vpre0[2], vpre1[2], mpre[4];
  const int kt0 = s * KT_PER;
  PREF_TILE(kt0);

  for (int kti = 0; kti < KT_PER; kti++) {
    __syncthreads();  // previous iteration's LDS reads done
    // ---- write staged tile to LDS ----
#pragma unroll
    for (int i = 0; i < 4; i++) {
      int e = tid + i * 128;
      *(u32x4*)&Klds[e >> 3][(e & 7) * 8] = kpre[i];
    }
#pragma unroll
    for (int i = 0; i < 2; i++) {
      int task = tid * 2 + i;
      int kpp = task >> 3, dc = task & 7;
#pragma unroll
      for (int j = 0; j < 8; j++) {
        u32 lo = (vpre0[i][j >> 1] >> ((j & 1) * 16)) & 0xFFFFu;
        u32 hi = (vpre1[i][j >> 1] >> ((j & 1) * 16)) & 0xFFFFu;
        *(u32*)&Vlds[dc * 8 + j][kpp * 2] = lo | (hi << 16);
      }
    }
    {  // pack 16 int32 mask values -> 16 bits
      u32 bb = 0;
#pragma unroll
      for (int c = 0; c < 4; c++)
#pragma unroll
        for (int j = 0; j < 4; j++) bb |= (mpre[c][j] ? 1u : 0u) << (c * 4 + j);
      Mbits[tid >> 2][tid & 3] = (u16)bb;
    }
    if (kti + 1 < KT_PER) { PREF_TILE(kt0 + kti + 1); }
    __syncthreads();

    // ---- S = Q K^T (strip 16 q-rows x 64 keys per wave) ----
    f32x4 sacc[4];
#pragma unroll
    for (int nt = 0; nt < 4; nt++) {
      sacc[nt] = zero4();
      bf16x8 b0 = *(const bf16x8*)&Klds[nt * 16 + li][g * 8];
      bf16x8 b1 = *(const bf16x8*)&Klds[nt * 16 + li][g * 8 + 32];
      sacc[nt] = mfma16(qf0, b0, sacc[nt]);
      sacc[nt] = mfma16(qf1, b1, sacc[nt]);
    }
    // ---- mask + online softmax ----
    float p_[4][4];
#pragma unroll
    for (int j = 0; j < 4; j++) {
      u64 rowbits = *(const u64*)&Mbits[w * 16 + g * 4 + j][0];
      float mx = -1e30f;
#pragma unroll
      for (int nt = 0; nt < 4; nt++) {
        float sv = sacc[nt][j] * INV_T;
        if ((rowbits >> (nt * 16 + li)) & 1) sv = -1e30f;
        p_[nt][j] = sv;
        mx = fmaxf(mx, sv);
      }
#pragma unroll
      for (int d = 1; d < 16; d <<= 1) mx = fmaxf(mx, __shfl_xor(mx, d, 64));
      float mn = fmaxf(m_[j], mx);
      float esc = __expf(m_[j] - mn);
      m_[j] = mn;
      float rs = 0.f;
#pragma unroll
      for (int nt = 0; nt < 4; nt++) {
        float pv = __expf(p_[nt][j] - mn);
        p_[nt][j] = pv;
        rs += pv;
      }
#pragma unroll
      for (int d = 1; d < 16; d <<= 1) rs += __shfl_xor(rs, d, 64);
      lsum[j] = lsum[j] * esc + rs;
#pragma unroll
      for (int dt = 0; dt < 4; dt++) o[dt][j] *= esc;
    }
    // ---- P -> LDS (D-layout scatter), then PV via MFMA ----
#pragma unroll
    for (int nt = 0; nt < 4; nt++)
#pragma unroll
      for (int j = 0; j < 4; j++)
        Plds[w][g * 4 + j][nt * 16 + li] = f2bf(p_[nt][j]);
#pragma unroll
    for (int ks = 0; ks < 2; ks++) {
      bf16x8 pa = *(const bf16x8*)&Plds[w][li][g * 8 + ks * 32];
#pragma unroll
      for (int dt = 0; dt < 4; dt++) {
        bf16x8 vb = *(const bf16x8*)&Vlds[dt * 16 + li][g * 8 + ks * 32];
        o[dt] = mfma16(pa, vb, o[dt]);
      }
    }
  }
  // ---- store unnormalized partials ----
#pragma unroll
  for (int j = 0; j < 4; j++) {
    size_t r = brow + q0 + w * 16 + g * 4 + j;
    size_t base = (r * KSPLIT + s) * 64;
#pragma unroll
    for (int dt = 0; dt < 4; dt++) po[base + dt * 16 + li] = o[dt][j];
    if (li == 0) {
      pm[r * KSPLIT + s] = m_[j];
      pl[r * KSPLIT + s] = lsum[j];
    }
  }
}

// ---------------------------------------------------------------------------
// Combine k-split partials: out = sum_i e^{m_i-M} o_i / sum_i e^{m_i-M} l_i
// (an all-masked split has m_i = -1e30 -> weight 0, self-neutralizing)
// ---------------------------------------------------------------------------
__global__ __launch_bounds__(256) void mha_comb(const float* __restrict__ po,
                                                const float* __restrict__ pm,
                                                const float* __restrict__ pl,
                                                u16* __restrict__ aout) {
  int id = blockIdx.x * 256 + threadIdx.x;
  int r = id >> 6, d = id & 63;
  float mv[KSPLIT];
  float M = -1e30f;
#pragma unroll
  for (int i = 0; i < KSPLIT; i++) {
    mv[i] = pm[r * KSPLIT + i];
    M = fmaxf(M, mv[i]);
  }
  float L = 0.f, acc = 0.f;
#pragma unroll
  for (int i = 0; i < KSPLIT; i++) {
    float wf = __expf(mv[i] - M);
    L += wf * pl[r * KSPLIT + i];
    acc += wf * po[((size_t)(r * KSPLIT + i)) * 64 + d];
  }
  aout[(size_t)r * 64 + d] = f2bf(acc / L);
}

// ---------------------------------------------------------------------------
// Final: out[r][m] = sum_d aout[r][d] * WpEff[m][d] + bp[m]   (fp32 out)
// ---------------------------------------------------------------------------
__global__ __launch_bounds__(128) void mha_fin(const u16* __restrict__ aout,
                                               const u16* __restrict__ WpT,
                                               const float* __restrict__ bp,
                                               float* __restrict__ out) {
  const int tid = threadIdx.x;
  const int w = tid >> 6, l = tid & 63, g = l >> 4, li = l & 15;
  const size_t r0 = (size_t)blockIdx.x * 32;
  const u16* ar = aout + (r0 + w * 16 + li) * 64;
  bf16x8 a0 = *(const bf16x8*)(ar + g * 8);
  bf16x8 a1 = *(const bf16x8*)(ar + g * 8 + 32);
#pragma unroll 4
  for (int nt = 0; nt < 32; nt++) {
    bf16x8 b0 = *(const bf16x8*)(WpT + (nt * 16 + li) * 72 + g * 8);
    bf16x8 b1 = *(const bf16x8*)(WpT + (nt * 16 + li) * 72 + g * 8 + 32);
    f32x4 acc = zero4();
    acc = mfma16(a0, b0, acc);
    acc = mfma16(a1, b1, acc);
    float bias = bp[nt * 16 + li];
#pragma unroll
    for (int j = 0; j < 4; j++)
      out[(r0 + w * 16 + g * 4 + j) * 512 + nt * 16 + li] = acc[j] + bias;
  }
}

extern "C" void kernel_launch(void* const* d_in, const int* in_sizes, int n_in,
                              void* d_out, int out_size, void* d_ws,
                              size_t ws_size, hipStream_t stream) {
  const float* q = (const float*)d_in[0];
  const float* k = (const float*)d_in[1];
  const float* v = (const float*)d_in[2];
  const int* mask = (const int*)d_in[3];  // jnp.bool_ -> int32 per harness
  const float* Wq = (const float*)d_in[4];
  const float* bq = (const float*)d_in[5];
  const float* Wk = (const float*)d_in[6];
  const float* bk = (const float*)d_in[7];
  const float* Wv = (const float*)d_in[8];
  const float* bv = (const float*)d_in[9];
  const float* Wp = (const float*)d_in[10];
  const float* bp = (const float*)d_in[11];

  char* ws = (char*)d_ws;
  u16* qkv16 = (u16*)(ws + 0);            // 3 * 1 MiB bf16 qp/kp/vp
  u16* aout = (u16*)(ws + 3145728);       // 1 MiB bf16 attention out
  u16* WtT = (u16*)(ws + 4194304);        // [3][64][520] bf16
  float* bqkv = (float*)(ws + 4393984);   // [192] f32
  u16* WpT = (u16*)(ws + 4394752);        // [512][72] bf16 (ends 4468480)
  float* po = (float*)(ws + 4468736);     // [8192*8][64] f32 = 16.78 MB
  float* pm = (float*)(ws + 21245952);    // [8192*8] f32
  float* pl = (float*)(ws + 21508096);    // [8192*8] f32 (ends 21770240)

  mha_prep<<<dim3(513), dim3(256), 0, stream>>>(Wq, Wk, Wv, bq, bk, bv, Wp,
                                                WtT, bqkv, WpT);
  mha_proj<<<dim3(256), dim3(256), 0, stream>>>(q, k, v, WtT, bqkv, qkv16);
  mha_attn<<<dim3(64, 4, KSPLIT), dim3(128), 0, stream>>>(qkv16, mask, po, pm,
                                                          pl);
  mha_comb<<<dim3(2048), dim3(256), 0, stream>>>(po, pm, pl, aout);
  mha_fin<<<dim3(256), dim3(128), 0, stream>>>(aout, WpT, bp, (float*)d_out);
}